// Round 8
// baseline (729.065 us; speedup 1.0000x reference)
//
#include <hip/hip_runtime.h>
#include <cstdint>

typedef float floatx4 __attribute__((ext_vector_type(4)));
typedef float floatx16 __attribute__((ext_vector_type(16)));
typedef int intx8 __attribute__((ext_vector_type(8)));

__device__ __forceinline__ unsigned short f2b(float f) {
  union { float f; unsigned u; } v; v.f = f;
  return (unsigned short)((v.u + 0x7FFFu + ((v.u >> 16) & 1u)) >> 16);
}
__device__ __forceinline__ float b2f(unsigned short h) {
  union { unsigned u; float f; } v; v.u = ((unsigned)h) << 16;
  return v.f;
}

__device__ __forceinline__ void gload_lds16(const void* g, void* l) {
  __builtin_amdgcn_global_load_lds(
      (const __attribute__((address_space(1))) void*)g,
      (__attribute__((address_space(3))) void*)l, 16, 0, 0);
}

// Read 32B fragment from 16B-XOR-swizzled LDS via two explicit 16B offsets.
__device__ __forceinline__ intx8 lds_read32s(const unsigned char* base,
                                             int lo, int hi) {
  union { intx8 v; int4 q[2]; } u;
  u.q[0] = *(const int4*)(base + lo);
  u.q[1] = *(const int4*)(base + hi);
  return u.v;
}

// Staging source byte-column: LDS seg-position p (=lane&7) of row r receives
// global seg p^(r&7); row-in-chunk = lane>>3.
__device__ __forceinline__ int swz_scol(int lane) {
  return (((lane & 7) ^ ((lane >> 3) & 7)) << 4);
}

// ---------------- fused prep kernel (4 ops, 1 launch) ----------------
__global__ __launch_bounds__(256) void prep_kernel(
    const float* __restrict__ W1, const float* __restrict__ W2,
    const float* __restrict__ wconv, const float* __restrict__ x,
    int* __restrict__ W1f8, int* __restrict__ W2f8,
    int* __restrict__ T8, unsigned char* __restrict__ xT) {
  const int bid = blockIdx.x;
  const int tid = threadIdx.x;
  if (bid < 8192) {
    const float* in = (bid < 4096) ? W1 : W2;
    int* out = (bid < 4096) ? W1f8 : W2f8;
    long i = (long)(bid & 4095) * 256 + tid;
    float4 v = ((const float4*)in)[i];
    int pk = __builtin_amdgcn_cvt_pk_fp8_f32(v.x * 64.0f, v.y * 64.0f, 0, false);
    pk = __builtin_amdgcn_cvt_pk_fp8_f32(v.z * 64.0f, v.w * 64.0f, pk, true);
    out[i] = pk;
  } else if (bid < 12288) {
    long i = (long)(bid - 8192) * 256 + tid;
    int n = (int)(i >> 9);
    int m0 = (int)(i & 511) * 4;
    float v[4];
#pragma unroll
    for (int r = 0; r < 4; ++r) {
      int m = m0 + r;
      v[r] = (m <= n) ? wconv[n - m] * 64.0f : 0.0f;
    }
    int pk = __builtin_amdgcn_cvt_pk_fp8_f32(v[0], v[1], 0, false);
    pk = __builtin_amdgcn_cvt_pk_fp8_f32(v[2], v[3], pk, true);
    T8[i] = pk;
  } else {
    __shared__ float tile[32][33];
    const int t = bid - 12288;
    const int d0 = (t & 31) * 32;
    const int n0 = ((t >> 5) & 63) * 32;
    const int b = t >> 11;
    const int tx = tid & 31;
    const int ty = tid >> 5;  // 0..7
    for (int i = ty; i < 32; i += 8)
      tile[i][tx] = x[((long)b * 2048 + n0 + i) * 1024 + d0 + tx];
    __syncthreads();
    float a = tile[ty * 4 + 0][tx];
    float c = tile[ty * 4 + 1][tx];
    float e = tile[ty * 4 + 2][tx];
    float f = tile[ty * 4 + 3][tx];
    int pk = __builtin_amdgcn_cvt_pk_fp8_f32(a, c, 0, false);
    pk = __builtin_amdgcn_cvt_pk_fp8_f32(e, f, pk, true);
    *(int*)(xT + ((long)b * 1024 + d0 + tx) * 2048 + n0 + ty * 4) = pk;
  }
}

// ---------------- fp8 GEMM 128x128: C = A @ B^T ----------------
// 2-phase sync-drain; LDS 32 KB (1024-stride chunks, XOR swizzle balances
// banks) -> 5 blocks/CU (20 waves/CU TLP).  MFMA 32x32x64, UNSWAPPED
// operands: D lane -> C column (32 consecutive cols per wave) so the
// epilogue's 2B/4B stores are coalesced ACROSS LANES (r7 lesson: the
// swapped layout made per-lane 8B stores row-strided -> 8x write
// amplification, WRITE_SIZE 32MB -> 1GB, 7x regression).
// EPI 0: Cb = bf16(acc)                (split-K partial)
// EPI 2: C8 = fp8(gelu_pade(acc+bias)) (MLP up)
template <int EPI, int NT, bool TRI>
__global__ __launch_bounds__(256, 5) void gemm_f8(
    const unsigned char* __restrict__ A, const unsigned char* __restrict__ B,
    int Kstride, int Kloop, long zsA, long zsB, long zsC, long zsP,
    int rx, int ryb, int gxn, unsigned sclA, unsigned sclB,
    const float* __restrict__ bias,
    unsigned short* __restrict__ Cb, unsigned char* __restrict__ C8) {
  __shared__ __align__(16) unsigned char As[16 * 1024];
  __shared__ __align__(16) unsigned char Bs[16 * 1024];
  const int tid = threadIdx.x;
  const int wid = tid >> 6;
  const int lane = tid & 63;
  const int l32 = lane & 31;
  const int half = lane >> 5;
  const int wm = (wid >> 1) * 64;
  const int wn = (wid & 1) * 64;

  const int bid = blockIdx.x;
  const int xcd = bid & 7;
  const int ib = bid >> 3;
  long bm, bn;
  int kstart, kend;
  long pofs = 0;
  if (TRI) {
    // ib in [0,32): ci = d-tile (8), ri = row-set (2), sp = K-split (2)
    const int ci = ib & 7;
    const int ri = (ib >> 3) & 1;
    const int sp = ib >> 4;
    bm = (long)(ri == 0 ? xcd : 15 - xcd) * 128;
    bn = (long)ci * 128;
    const int T = (int)(bm >> 7) + 1;      // K-tiles for this row
    const int h = (T + 1) >> 1;            // split point (sp0 gets ceil)
    kstart = (sp ? h : 0) * 128;
    kend = (sp ? T : h) * 128;
    pofs = (long)sp * zsP;
  } else {
    const int ci = ib % rx;
    const int ri = ib / rx;
    const int gx = xcd % gxn;
    const int gy = xcd / gxn;
    bm = (long)(gy * ryb + ri) * 128;
    bn = (long)(gx * rx + ci) * 128;
    kstart = 0;
    kend = Kloop;
  }
  const int bz = blockIdx.z;
  const unsigned char* Ab = A + zsA * bz;
  const unsigned char* Bb = B + zsB * bz;

  floatx16 acc[2][2];
#pragma unroll
  for (int i = 0; i < 2; ++i)
#pragma unroll
    for (int j = 0; j < 2; ++j)
#pragma unroll
      for (int e = 0; e < 16; ++e) acc[i][j][e] = 0.0f;

  const int srow = tid >> 3;
  const int scol = swz_scol(lane);   // pre-swizzled source column (16B gran)
  const unsigned char* gA[4];
  const unsigned char* gB[4];
  unsigned char* lA[4];
  unsigned char* lB[4];
#pragma unroll
  for (int p = 0; p < 4; ++p) {
    gA[p] = Ab + (bm + p * 32 + srow) * (long)Kstride + scol;
    gB[p] = Bb + (bn + p * 32 + srow) * (long)Kstride + scol;
    lA[p] = As + (p * 4 + wid) * 1024;  // wave-uniform base (+lane*16 implicit)
    lB[p] = Bs + (p * 4 + wid) * 1024;
  }

  // frag (i,s): rows wm+i*32+l32, global 16B segs q0 = s*4+half*2 and q0+1;
  // stored at position q^(row&7).  base = row*128 (1024-stride chunks).
  int offA_lo[2][2], offA_hi[2][2], offB_lo[2][2], offB_hi[2][2];
#pragma unroll
  for (int i = 0; i < 2; ++i)
#pragma unroll
    for (int s = 0; s < 2; ++s) {
      const int q0 = s * 4 + half * 2;
      const int ra = (int)wm + i * 32 + l32;
      const int baseA = ra * 128;
      offA_lo[i][s] = baseA + ((q0 ^ (ra & 7)) << 4);
      offA_hi[i][s] = baseA + (((q0 + 1) ^ (ra & 7)) << 4);
      const int rb = (int)wn + i * 32 + l32;
      const int baseB = rb * 128;
      offB_lo[i][s] = baseB + ((q0 ^ (rb & 7)) << 4);
      offB_hi[i][s] = baseB + (((q0 + 1) ^ (rb & 7)) << 4);
    }

  for (int kk = kstart; kk < kend; kk += 128) {
    __syncthreads();
#pragma unroll
    for (int p = 0; p < 4; ++p) {
      gload_lds16(gA[p] + kk, lA[p]);
      gload_lds16(gB[p] + kk, lB[p]);
    }
    __syncthreads();
#pragma unroll
    for (int s = 0; s < 2; ++s) {
      intx8 b0 = lds_read32s(Bs, offB_lo[0][s], offB_hi[0][s]);
      intx8 b1 = lds_read32s(Bs, offB_lo[1][s], offB_hi[1][s]);
      intx8 a0 = lds_read32s(As, offA_lo[0][s], offA_hi[0][s]);
      intx8 a1 = lds_read32s(As, offA_lo[1][s], offA_hi[1][s]);
      acc[0][0] = __builtin_amdgcn_mfma_scale_f32_32x32x64_f8f6f4(
          a0, b0, acc[0][0], 0, 0, 0, sclA, 0, sclB);
      acc[0][1] = __builtin_amdgcn_mfma_scale_f32_32x32x64_f8f6f4(
          a0, b1, acc[0][1], 0, 0, 0, sclA, 0, sclB);
      acc[1][0] = __builtin_amdgcn_mfma_scale_f32_32x32x64_f8f6f4(
          a1, b0, acc[1][0], 0, 0, 0, sclA, 0, sclB);
      acc[1][1] = __builtin_amdgcn_mfma_scale_f32_32x32x64_f8f6f4(
          a1, b1, acc[1][1], 0, 0, 0, sclA, 0, sclB);
    }
  }

  // C/D frag (HW-verified): col = lane&31, row = (r&3)+8*(r>>2)+4*half
  // -> 32 lanes write 32 consecutive cols: coalesced.
#pragma unroll
  for (int i = 0; i < 2; ++i)
#pragma unroll
    for (int j = 0; j < 2; ++j)
#pragma unroll
      for (int r = 0; r < 16; ++r) {
        long row = bm + wm + i * 32 + (r & 3) + 8 * (r >> 2) + 4 * half;
        long col = bn + wn + j * 32 + l32;
        long idx = pofs + (long)bz * zsC + row * (long)NT + col;
        float v = acc[i][j][r];
        if (EPI == 0) {
          Cb[idx] = f2b(v);
        } else {
          v += bias[col];
          float u = v * (0.7978845608f + 0.0356774081f * v * v);
          float u2 = u * u;
          float t = __fdividef(u * (15.0f + u2), 15.0f + 6.0f * u2);
          t = fminf(fmaxf(t, -1.0f), 1.0f);
          float g = 0.5f * v * (1.0f + t);
          int pk = __builtin_amdgcn_cvt_pk_fp8_f32(g, 0.0f, 0, false);
          C8[idx] = (unsigned char)(pk & 0xFF);
        }
      }
}

// ---------------- LN1 fused: v = x + scale[n]*(c0+c1); LN -> bf16 + fp8 ----
__global__ __launch_bounds__(256) void ln1_kernel(
    const float* __restrict__ x, const unsigned short* __restrict__ c0,
    const unsigned short* __restrict__ c1, const float* __restrict__ scale,
    const float* __restrict__ w, const float* __restrict__ b,
    unsigned short* __restrict__ outb, int* __restrict__ outf8) {
  const long row = blockIdx.x;
  const int tid = threadIdx.x;
  float4 xv = ((const float4*)x)[row * 256 + tid];
  ushort4 a4 = ((const ushort4*)c0)[row * 256 + tid];
  ushort4 e4 = ((const ushort4*)c1)[row * 256 + tid];
  const float sc = scale[row & 2047];
  float4 v;
  v.x = xv.x + sc * (b2f(a4.x) + b2f(e4.x));
  v.y = xv.y + sc * (b2f(a4.y) + b2f(e4.y));
  v.z = xv.z + sc * (b2f(a4.z) + b2f(e4.z));
  v.w = xv.w + sc * (b2f(a4.w) + b2f(e4.w));
  float s = v.x + v.y + v.z + v.w;
  float ss = v.x * v.x + v.y * v.y + v.z * v.z + v.w * v.w;
#pragma unroll
  for (int off = 32; off > 0; off >>= 1) {
    s += __shfl_down(s, off);
    ss += __shfl_down(ss, off);
  }
  __shared__ float red[8];
  const int wid = tid >> 6, lane = tid & 63;
  if (lane == 0) { red[wid] = s; red[4 + wid] = ss; }
  __syncthreads();
  s = red[0] + red[1] + red[2] + red[3];
  ss = red[4] + red[5] + red[6] + red[7];
  const float mu = s * (1.0f / 1024.0f);
  const float var = ss * (1.0f / 1024.0f) - mu * mu;
  const float rs = rsqrtf(var + 1e-5f);
  float4 wv = ((const float4*)w)[tid];
  float4 bv = ((const float4*)b)[tid];
  float o0 = (v.x - mu) * rs * wv.x + bv.x;
  float o1 = (v.y - mu) * rs * wv.y + bv.y;
  float o2 = (v.z - mu) * rs * wv.z + bv.z;
  float o3 = (v.w - mu) * rs * wv.w + bv.w;
  ushort4 u{f2b(o0), f2b(o1), f2b(o2), f2b(o3)};
  ((ushort4*)outb)[row * 256 + tid] = u;
  int pk = __builtin_amdgcn_cvt_pk_fp8_f32(o0, o1, 0, false);
  pk = __builtin_amdgcn_cvt_pk_fp8_f32(o2, o3, pk, true);
  outf8[row * 256 + tid] = pk;
}

// LN2 fused: v = x1 + scalar*(y0+y1+b2); out = LN(v)*w + b
__global__ __launch_bounds__(256) void ln2_fused_kernel(
    const unsigned short* __restrict__ y0, const unsigned short* __restrict__ y1,
    const unsigned short* __restrict__ x1b, const float* __restrict__ b2,
    const float* __restrict__ scalar_p, const float* __restrict__ w,
    const float* __restrict__ b, float* __restrict__ out) {
  const long row = blockIdx.x;
  const int tid = threadIdx.x;
  ushort4 a4 = ((const ushort4*)y0)[row * 256 + tid];
  ushort4 c4 = ((const ushort4*)y1)[row * 256 + tid];
  ushort4 xr = ((const ushort4*)x1b)[row * 256 + tid];
  float4 bias = ((const float4*)b2)[tid];
  const float scl = scalar_p[0];
  float4 v;
  v.x = b2f(xr.x) + scl * (b2f(a4.x) + b2f(c4.x) + bias.x);
  v.y = b2f(xr.y) + scl * (b2f(a4.y) + b2f(c4.y) + bias.y);
  v.z = b2f(xr.z) + scl * (b2f(a4.z) + b2f(c4.z) + bias.z);
  v.w = b2f(xr.w) + scl * (b2f(a4.w) + b2f(c4.w) + bias.w);
  float s = v.x + v.y + v.z + v.w;
  float ss = v.x * v.x + v.y * v.y + v.z * v.z + v.w * v.w;
#pragma unroll
  for (int off = 32; off > 0; off >>= 1) {
    s += __shfl_down(s, off);
    ss += __shfl_down(ss, off);
  }
  __shared__ float red[8];
  const int wid = tid >> 6, lane = tid & 63;
  if (lane == 0) { red[wid] = s; red[4 + wid] = ss; }
  __syncthreads();
  s = red[0] + red[1] + red[2] + red[3];
  ss = red[4] + red[5] + red[6] + red[7];
  const float mu = s * (1.0f / 1024.0f);
  const float var = ss * (1.0f / 1024.0f) - mu * mu;
  const float rs = rsqrtf(var + 1e-5f);
  float4 wv = ((const float4*)w)[tid];
  float4 bv = ((const float4*)b)[tid];
  float4 o;
  o.x = (v.x - mu) * rs * wv.x + bv.x;
  o.y = (v.y - mu) * rs * wv.y + bv.y;
  o.z = (v.z - mu) * rs * wv.z + bv.z;
  o.w = (v.w - mu) * rs * wv.w + bv.w;
  ((float4*)out)[row * 256 + tid] = o;
}

// ---------------- launch ----------------
extern "C" void kernel_launch(void* const* d_in, const int* in_sizes, int n_in,
                              void* d_out, int out_size, void* d_ws, size_t ws_size,
                              hipStream_t stream) {
  const float* x      = (const float*)d_in[0];
  const float* wconv  = (const float*)d_in[1];
  const float* scale  = (const float*)d_in[2];
  const float* ln1w   = (const float*)d_in[3];
  const float* ln1b   = (const float*)d_in[4];
  const float* W1     = (const float*)d_in[5];
  const float* b1     = (const float*)d_in[6];
  const float* W2     = (const float*)d_in[7];
  const float* b2     = (const float*)d_in[8];
  const float* scalar = (const float*)d_in[9];
  const float* ln2w   = (const float*)d_in[10];
  const float* ln2b   = (const float*)d_in[11];
  float* out = (float*)d_out;

  const unsigned SCL_1  = 0x7F7F7F7Fu;  // 2^0 per-block scales
  const unsigned SCL_64 = 0x79797979u;  // 2^-6 (operand pre-scaled x64)

  char* ws = (char*)d_ws;
  unsigned char* xT8   = (unsigned char*)ws;  ws += (size_t)4 * 1024 * 2048;
  unsigned char* T8    = (unsigned char*)ws;  ws += (size_t)2048 * 2048;
  unsigned char* W1f8  = (unsigned char*)ws;  ws += (size_t)4096 * 1024;
  unsigned char* W2f8  = (unsigned char*)ws;  ws += (size_t)4096 * 1024;
  float* y             = (float*)ws;          ws += (size_t)8192 * 1024 * 4;  // unused (kept)
  unsigned short* yb   = (unsigned short*)ws; ws += (size_t)2 * 8192 * 1024 * 2;
  unsigned short* x1b  = (unsigned short*)ws; ws += (size_t)8192 * 1024 * 2;
  unsigned char* x1f8  = (unsigned char*)ws;  ws += (size_t)8192 * 1024;
  unsigned char* h8    = (unsigned char*)ws;  ws += (size_t)8192 * 4096;
  (void)y;

  // prep: all 4 casts/builds in one launch
  prep_kernel<<<20480, 256, 0, stream>>>(W1, W2, wconv, x,
                                         (int*)W1f8, (int*)W2f8, (int*)T8, xT8);

  // GEMM1 (fp8, TRI, split-K=2): conv partials (bf16) = T @ xT_b^T -> yb0/yb1
  gemm_f8<0, 1024, true><<<dim3(256, 1, 4), 256, 0, stream>>>(
      T8, xT8, 2048, 2048, 0L, (long)1024 * 2048, (long)2048 * 1024,
      (long)8192 * 1024, 8, 0, 0, SCL_64, SCL_1, nullptr, yb, nullptr);
  // LN1 fused: x1 = LN(x + scale*(c0+c1)) -> bf16 residual + fp8 operand
  ln1_kernel<<<8192, 256, 0, stream>>>(
      x, yb, yb + (size_t)8192 * 1024, scale, ln1w, ln1b, x1b, (int*)x1f8);
  // GEMM2 (fp8): h = gelu(x1 @ W1^T + b1) -> fp8; rect 16x16, XCD grid 2 wide
  gemm_f8<2, 4096, false><<<dim3(2048, 1, 1), 256, 0, stream>>>(
      x1f8, W1f8, 1024, 1024, 0L, 0L, 0L, 0L,
      16, 16, 2, SCL_1, SCL_64, b1, nullptr, h8);
  // GEMM3 (fp8) split-K=2: yb = bf16 partial h @ W2^T; rect 8x8 per XCD
  gemm_f8<0, 1024, false><<<dim3(512, 1, 2), 256, 0, stream>>>(
      h8, W2f8, 4096, 2048, 2048L, 2048L, (long)8192 * 1024, 0L,
      8, 8, 1, SCL_1, SCL_64, nullptr, yb, nullptr);
  // LN2 fused: out = LN(x1 + scalar*(yb0+yb1+b2))
  ln2_fused_kernel<<<8192, 256, 0, stream>>>(
      yb, yb + (size_t)8192 * 1024, x1b, b2, scalar, ln2w, ln2b, out);
}

// Round 9
// 283.289 us; speedup vs baseline: 2.5736x; 2.5736x over previous
//
#include <hip/hip_runtime.h>
#include <cstdint>

typedef float floatx4 __attribute__((ext_vector_type(4)));
typedef float floatx16 __attribute__((ext_vector_type(16)));
typedef int intx8 __attribute__((ext_vector_type(8)));

__device__ __forceinline__ unsigned short f2b(float f) {
  union { float f; unsigned u; } v; v.f = f;
  return (unsigned short)((v.u + 0x7FFFu + ((v.u >> 16) & 1u)) >> 16);
}
__device__ __forceinline__ float b2f(unsigned short h) {
  union { unsigned u; float f; } v; v.u = ((unsigned)h) << 16;
  return v.f;
}

__device__ __forceinline__ void gload_lds16(const void* g, void* l) {
  __builtin_amdgcn_global_load_lds(
      (const __attribute__((address_space(1))) void*)g,
      (__attribute__((address_space(3))) void*)l, 16, 0, 0);
}

// Read 32B fragment from 16B-XOR-swizzled LDS via two explicit 16B offsets.
__device__ __forceinline__ intx8 lds_read32s(const unsigned char* base,
                                             int lo, int hi) {
  union { intx8 v; int4 q[2]; } u;
  u.q[0] = *(const int4*)(base + lo);
  u.q[1] = *(const int4*)(base + hi);
  return u.v;
}

// Staging source byte-column: LDS seg-position p (=lane&7) of row r receives
// global seg p^(r&7); row-in-chunk = lane>>3.
__device__ __forceinline__ int swz_scol(int lane) {
  return (((lane & 7) ^ ((lane >> 3) & 7)) << 4);
}

// ---------------- fused prep kernel (4 ops, 1 launch) ----------------
__global__ __launch_bounds__(256) void prep_kernel(
    const float* __restrict__ W1, const float* __restrict__ W2,
    const float* __restrict__ wconv, const float* __restrict__ x,
    int* __restrict__ W1f8, int* __restrict__ W2f8,
    int* __restrict__ T8, unsigned char* __restrict__ xT) {
  const int bid = blockIdx.x;
  const int tid = threadIdx.x;
  if (bid < 8192) {
    const float* in = (bid < 4096) ? W1 : W2;
    int* out = (bid < 4096) ? W1f8 : W2f8;
    long i = (long)(bid & 4095) * 256 + tid;
    float4 v = ((const float4*)in)[i];
    int pk = __builtin_amdgcn_cvt_pk_fp8_f32(v.x * 64.0f, v.y * 64.0f, 0, false);
    pk = __builtin_amdgcn_cvt_pk_fp8_f32(v.z * 64.0f, v.w * 64.0f, pk, true);
    out[i] = pk;
  } else if (bid < 12288) {
    long i = (long)(bid - 8192) * 256 + tid;
    int n = (int)(i >> 9);
    int m0 = (int)(i & 511) * 4;
    float v[4];
#pragma unroll
    for (int r = 0; r < 4; ++r) {
      int m = m0 + r;
      v[r] = (m <= n) ? wconv[n - m] * 64.0f : 0.0f;
    }
    int pk = __builtin_amdgcn_cvt_pk_fp8_f32(v[0], v[1], 0, false);
    pk = __builtin_amdgcn_cvt_pk_fp8_f32(v[2], v[3], pk, true);
    T8[i] = pk;
  } else {
    __shared__ float tile[32][33];
    const int t = bid - 12288;
    const int d0 = (t & 31) * 32;
    const int n0 = ((t >> 5) & 63) * 32;
    const int b = t >> 11;
    const int tx = tid & 31;
    const int ty = tid >> 5;  // 0..7
    for (int i = ty; i < 32; i += 8)
      tile[i][tx] = x[((long)b * 2048 + n0 + i) * 1024 + d0 + tx];
    __syncthreads();
    float a = tile[ty * 4 + 0][tx];
    float c = tile[ty * 4 + 1][tx];
    float e = tile[ty * 4 + 2][tx];
    float f = tile[ty * 4 + 3][tx];
    int pk = __builtin_amdgcn_cvt_pk_fp8_f32(a, c, 0, false);
    pk = __builtin_amdgcn_cvt_pk_fp8_f32(e, f, pk, true);
    *(int*)(xT + ((long)b * 1024 + d0 + tx) * 2048 + n0 + ty * 4) = pk;
  }
}

// ---------------- fp8 GEMM 128x128: C = A @ B^T ----------------
// 2-phase sync-drain; LDS 32 KB (1024-stride chunks, XOR swizzle).
// __launch_bounds__(256,4): the kernel uses ~128 regs/thread (64 arch VGPR
// + 64 acc) which EXACTLY fits the 512/4 cap.  (256,5) caps at ~102 and
// SPILLS THE ACCUMULATOR to scratch: r7/r8's 300-1000 MB FETCH/WRITE and
// 5x regression.  Rule: VGPR_Count below the acc footprint == spill.
// MFMA 32x32x64, unswapped: D lane -> C column -> coalesced 2B/1B stores.
// EPI 0: Cb = bf16(acc)                (split-K partial)
// EPI 2: C8 = fp8(gelu_pade(acc+bias)) (MLP up)
template <int EPI, int NT, bool TRI>
__global__ __launch_bounds__(256, 4) void gemm_f8(
    const unsigned char* __restrict__ A, const unsigned char* __restrict__ B,
    int Kstride, int Kloop, long zsA, long zsB, long zsC, long zsP,
    int rx, int ryb, int gxn, unsigned sclA, unsigned sclB,
    const float* __restrict__ bias,
    unsigned short* __restrict__ Cb, unsigned char* __restrict__ C8) {
  __shared__ __align__(16) unsigned char As[16 * 1024];
  __shared__ __align__(16) unsigned char Bs[16 * 1024];
  const int tid = threadIdx.x;
  const int wid = tid >> 6;
  const int lane = tid & 63;
  const int l32 = lane & 31;
  const int half = lane >> 5;
  const int wm = (wid >> 1) * 64;
  const int wn = (wid & 1) * 64;

  const int bid = blockIdx.x;
  const int xcd = bid & 7;
  const int ib = bid >> 3;
  long bm, bn;
  int kstart, kend;
  long pofs = 0;
  if (TRI) {
    // ib in [0,32): ci = d-tile (8), ri = row-set (2), sp = K-split (2)
    const int ci = ib & 7;
    const int ri = (ib >> 3) & 1;
    const int sp = ib >> 4;
    bm = (long)(ri == 0 ? xcd : 15 - xcd) * 128;
    bn = (long)ci * 128;
    const int T = (int)(bm >> 7) + 1;      // K-tiles for this row
    const int h = (T + 1) >> 1;            // split point (sp0 gets ceil)
    kstart = (sp ? h : 0) * 128;
    kend = (sp ? T : h) * 128;
    pofs = (long)sp * zsP;
  } else {
    const int ci = ib % rx;
    const int ri = ib / rx;
    const int gx = xcd % gxn;
    const int gy = xcd / gxn;
    bm = (long)(gy * ryb + ri) * 128;
    bn = (long)(gx * rx + ci) * 128;
    kstart = 0;
    kend = Kloop;
  }
  const int bz = blockIdx.z;
  const unsigned char* Ab = A + zsA * bz;
  const unsigned char* Bb = B + zsB * bz;

  floatx16 acc[2][2];
#pragma unroll
  for (int i = 0; i < 2; ++i)
#pragma unroll
    for (int j = 0; j < 2; ++j)
#pragma unroll
      for (int e = 0; e < 16; ++e) acc[i][j][e] = 0.0f;

  const int srow = tid >> 3;
  const int scol = swz_scol(lane);   // pre-swizzled source column (16B gran)
  const unsigned char* gA[4];
  const unsigned char* gB[4];
  unsigned char* lA[4];
  unsigned char* lB[4];
#pragma unroll
  for (int p = 0; p < 4; ++p) {
    gA[p] = Ab + (bm + p * 32 + srow) * (long)Kstride + scol;
    gB[p] = Bb + (bn + p * 32 + srow) * (long)Kstride + scol;
    lA[p] = As + (p * 4 + wid) * 1024;  // wave-uniform base (+lane*16 implicit)
    lB[p] = Bs + (p * 4 + wid) * 1024;
  }

  // frag (i,s): rows wm+i*32+l32, global 16B segs q0 = s*4+half*2 and q0+1;
  // stored at position q^(row&7).  base = row*128 (1024-stride chunks).
  int offA_lo[2][2], offA_hi[2][2], offB_lo[2][2], offB_hi[2][2];
#pragma unroll
  for (int i = 0; i < 2; ++i)
#pragma unroll
    for (int s = 0; s < 2; ++s) {
      const int q0 = s * 4 + half * 2;
      const int ra = (int)wm + i * 32 + l32;
      const int baseA = ra * 128;
      offA_lo[i][s] = baseA + ((q0 ^ (ra & 7)) << 4);
      offA_hi[i][s] = baseA + (((q0 + 1) ^ (ra & 7)) << 4);
      const int rb = (int)wn + i * 32 + l32;
      const int baseB = rb * 128;
      offB_lo[i][s] = baseB + ((q0 ^ (rb & 7)) << 4);
      offB_hi[i][s] = baseB + (((q0 + 1) ^ (rb & 7)) << 4);
    }

  for (int kk = kstart; kk < kend; kk += 128) {
    __syncthreads();
#pragma unroll
    for (int p = 0; p < 4; ++p) {
      gload_lds16(gA[p] + kk, lA[p]);
      gload_lds16(gB[p] + kk, lB[p]);
    }
    __syncthreads();
#pragma unroll
    for (int s = 0; s < 2; ++s) {
      intx8 b0 = lds_read32s(Bs, offB_lo[0][s], offB_hi[0][s]);
      intx8 b1 = lds_read32s(Bs, offB_lo[1][s], offB_hi[1][s]);
      intx8 a0 = lds_read32s(As, offA_lo[0][s], offA_hi[0][s]);
      intx8 a1 = lds_read32s(As, offA_lo[1][s], offA_hi[1][s]);
      acc[0][0] = __builtin_amdgcn_mfma_scale_f32_32x32x64_f8f6f4(
          a0, b0, acc[0][0], 0, 0, 0, sclA, 0, sclB);
      acc[0][1] = __builtin_amdgcn_mfma_scale_f32_32x32x64_f8f6f4(
          a0, b1, acc[0][1], 0, 0, 0, sclA, 0, sclB);
      acc[1][0] = __builtin_amdgcn_mfma_scale_f32_32x32x64_f8f6f4(
          a1, b0, acc[1][0], 0, 0, 0, sclA, 0, sclB);
      acc[1][1] = __builtin_amdgcn_mfma_scale_f32_32x32x64_f8f6f4(
          a1, b1, acc[1][1], 0, 0, 0, sclA, 0, sclB);
    }
  }

  // C/D frag (HW-verified): col = lane&31, row = (r&3)+8*(r>>2)+4*half
  // -> 32 lanes write 32 consecutive cols: coalesced.
#pragma unroll
  for (int i = 0; i < 2; ++i)
#pragma unroll
    for (int j = 0; j < 2; ++j)
#pragma unroll
      for (int r = 0; r < 16; ++r) {
        long row = bm + wm + i * 32 + (r & 3) + 8 * (r >> 2) + 4 * half;
        long col = bn + wn + j * 32 + l32;
        long idx = pofs + (long)bz * zsC + row * (long)NT + col;
        float v = acc[i][j][r];
        if (EPI == 0) {
          Cb[idx] = f2b(v);
        } else {
          v += bias[col];
          float u = v * (0.7978845608f + 0.0356774081f * v * v);
          float u2 = u * u;
          float t = __fdividef(u * (15.0f + u2), 15.0f + 6.0f * u2);
          t = fminf(fmaxf(t, -1.0f), 1.0f);
          float g = 0.5f * v * (1.0f + t);
          int pk = __builtin_amdgcn_cvt_pk_fp8_f32(g, 0.0f, 0, false);
          C8[idx] = (unsigned char)(pk & 0xFF);
        }
      }
}

// ---------------- LN1 fused: v = x + scale[n]*(c0+c1); LN -> bf16 + fp8 ----
__global__ __launch_bounds__(256) void ln1_kernel(
    const float* __restrict__ x, const unsigned short* __restrict__ c0,
    const unsigned short* __restrict__ c1, const float* __restrict__ scale,
    const float* __restrict__ w, const float* __restrict__ b,
    unsigned short* __restrict__ outb, int* __restrict__ outf8) {
  const long row = blockIdx.x;
  const int tid = threadIdx.x;
  float4 xv = ((const float4*)x)[row * 256 + tid];
  ushort4 a4 = ((const ushort4*)c0)[row * 256 + tid];
  ushort4 e4 = ((const ushort4*)c1)[row * 256 + tid];
  const float sc = scale[row & 2047];
  float4 v;
  v.x = xv.x + sc * (b2f(a4.x) + b2f(e4.x));
  v.y = xv.y + sc * (b2f(a4.y) + b2f(e4.y));
  v.z = xv.z + sc * (b2f(a4.z) + b2f(e4.z));
  v.w = xv.w + sc * (b2f(a4.w) + b2f(e4.w));
  float s = v.x + v.y + v.z + v.w;
  float ss = v.x * v.x + v.y * v.y + v.z * v.z + v.w * v.w;
#pragma unroll
  for (int off = 32; off > 0; off >>= 1) {
    s += __shfl_down(s, off);
    ss += __shfl_down(ss, off);
  }
  __shared__ float red[8];
  const int wid = tid >> 6, lane = tid & 63;
  if (lane == 0) { red[wid] = s; red[4 + wid] = ss; }
  __syncthreads();
  s = red[0] + red[1] + red[2] + red[3];
  ss = red[4] + red[5] + red[6] + red[7];
  const float mu = s * (1.0f / 1024.0f);
  const float var = ss * (1.0f / 1024.0f) - mu * mu;
  const float rs = rsqrtf(var + 1e-5f);
  float4 wv = ((const float4*)w)[tid];
  float4 bv = ((const float4*)b)[tid];
  float o0 = (v.x - mu) * rs * wv.x + bv.x;
  float o1 = (v.y - mu) * rs * wv.y + bv.y;
  float o2 = (v.z - mu) * rs * wv.z + bv.z;
  float o3 = (v.w - mu) * rs * wv.w + bv.w;
  ushort4 u{f2b(o0), f2b(o1), f2b(o2), f2b(o3)};
  ((ushort4*)outb)[row * 256 + tid] = u;
  int pk = __builtin_amdgcn_cvt_pk_fp8_f32(o0, o1, 0, false);
  pk = __builtin_amdgcn_cvt_pk_fp8_f32(o2, o3, pk, true);
  outf8[row * 256 + tid] = pk;
}

// LN2 fused: v = x1 + scalar*(y0+y1+b2); out = LN(v)*w + b
__global__ __launch_bounds__(256) void ln2_fused_kernel(
    const unsigned short* __restrict__ y0, const unsigned short* __restrict__ y1,
    const unsigned short* __restrict__ x1b, const float* __restrict__ b2,
    const float* __restrict__ scalar_p, const float* __restrict__ w,
    const float* __restrict__ b, float* __restrict__ out) {
  const long row = blockIdx.x;
  const int tid = threadIdx.x;
  ushort4 a4 = ((const ushort4*)y0)[row * 256 + tid];
  ushort4 c4 = ((const ushort4*)y1)[row * 256 + tid];
  ushort4 xr = ((const ushort4*)x1b)[row * 256 + tid];
  float4 bias = ((const float4*)b2)[tid];
  const float scl = scalar_p[0];
  float4 v;
  v.x = b2f(xr.x) + scl * (b2f(a4.x) + b2f(c4.x) + bias.x);
  v.y = b2f(xr.y) + scl * (b2f(a4.y) + b2f(c4.y) + bias.y);
  v.z = b2f(xr.z) + scl * (b2f(a4.z) + b2f(c4.z) + bias.z);
  v.w = b2f(xr.w) + scl * (b2f(a4.w) + b2f(c4.w) + bias.w);
  float s = v.x + v.y + v.z + v.w;
  float ss = v.x * v.x + v.y * v.y + v.z * v.z + v.w * v.w;
#pragma unroll
  for (int off = 32; off > 0; off >>= 1) {
    s += __shfl_down(s, off);
    ss += __shfl_down(ss, off);
  }
  __shared__ float red[8];
  const int wid = tid >> 6, lane = tid & 63;
  if (lane == 0) { red[wid] = s; red[4 + wid] = ss; }
  __syncthreads();
  s = red[0] + red[1] + red[2] + red[3];
  ss = red[4] + red[5] + red[6] + red[7];
  const float mu = s * (1.0f / 1024.0f);
  const float var = ss * (1.0f / 1024.0f) - mu * mu;
  const float rs = rsqrtf(var + 1e-5f);
  float4 wv = ((const float4*)w)[tid];
  float4 bv = ((const float4*)b)[tid];
  float4 o;
  o.x = (v.x - mu) * rs * wv.x + bv.x;
  o.y = (v.y - mu) * rs * wv.y + bv.y;
  o.z = (v.z - mu) * rs * wv.z + bv.z;
  o.w = (v.w - mu) * rs * wv.w + bv.w;
  ((float4*)out)[row * 256 + tid] = o;
}

// ---------------- launch ----------------
extern "C" void kernel_launch(void* const* d_in, const int* in_sizes, int n_in,
                              void* d_out, int out_size, void* d_ws, size_t ws_size,
                              hipStream_t stream) {
  const float* x      = (const float*)d_in[0];
  const float* wconv  = (const float*)d_in[1];
  const float* scale  = (const float*)d_in[2];
  const float* ln1w   = (const float*)d_in[3];
  const float* ln1b   = (const float*)d_in[4];
  const float* W1     = (const float*)d_in[5];
  const float* b1     = (const float*)d_in[6];
  const float* W2     = (const float*)d_in[7];
  const float* b2     = (const float*)d_in[8];
  const float* scalar = (const float*)d_in[9];
  const float* ln2w   = (const float*)d_in[10];
  const float* ln2b   = (const float*)d_in[11];
  float* out = (float*)d_out;

  const unsigned SCL_1  = 0x7F7F7F7Fu;  // 2^0 per-block scales
  const unsigned SCL_64 = 0x79797979u;  // 2^-6 (operand pre-scaled x64)

  char* ws = (char*)d_ws;
  unsigned char* xT8   = (unsigned char*)ws;  ws += (size_t)4 * 1024 * 2048;
  unsigned char* T8    = (unsigned char*)ws;  ws += (size_t)2048 * 2048;
  unsigned char* W1f8  = (unsigned char*)ws;  ws += (size_t)4096 * 1024;
  unsigned char* W2f8  = (unsigned char*)ws;  ws += (size_t)4096 * 1024;
  float* y             = (float*)ws;          ws += (size_t)8192 * 1024 * 4;  // unused (kept)
  unsigned short* yb   = (unsigned short*)ws; ws += (size_t)2 * 8192 * 1024 * 2;
  unsigned short* x1b  = (unsigned short*)ws; ws += (size_t)8192 * 1024 * 2;
  unsigned char* x1f8  = (unsigned char*)ws;  ws += (size_t)8192 * 1024;
  unsigned char* h8    = (unsigned char*)ws;  ws += (size_t)8192 * 4096;
  (void)y;

  // prep: all 4 casts/builds in one launch
  prep_kernel<<<20480, 256, 0, stream>>>(W1, W2, wconv, x,
                                         (int*)W1f8, (int*)W2f8, (int*)T8, xT8);

  // GEMM1 (fp8, TRI, split-K=2): conv partials (bf16) = T @ xT_b^T -> yb0/yb1
  gemm_f8<0, 1024, true><<<dim3(256, 1, 4), 256, 0, stream>>>(
      T8, xT8, 2048, 2048, 0L, (long)1024 * 2048, (long)2048 * 1024,
      (long)8192 * 1024, 8, 0, 0, SCL_64, SCL_1, nullptr, yb, nullptr);
  // LN1 fused: x1 = LN(x + scale*(c0+c1)) -> bf16 residual + fp8 operand
  ln1_kernel<<<8192, 256, 0, stream>>>(
      x, yb, yb + (size_t)8192 * 1024, scale, ln1w, ln1b, x1b, (int*)x1f8);
  // GEMM2 (fp8): h = gelu(x1 @ W1^T + b1) -> fp8; rect 16x16, XCD grid 2 wide
  gemm_f8<2, 4096, false><<<dim3(2048, 1, 1), 256, 0, stream>>>(
      x1f8, W1f8, 1024, 1024, 0L, 0L, 0L, 0L,
      16, 16, 2, SCL_1, SCL_64, b1, nullptr, h8);
  // GEMM3 (fp8) split-K=2: yb = bf16 partial h @ W2^T; rect 8x8 per XCD
  gemm_f8<0, 1024, false><<<dim3(512, 1, 2), 256, 0, stream>>>(
      h8, W2f8, 4096, 2048, 2048L, 2048L, (long)8192 * 1024, 0L,
      8, 8, 1, SCL_1, SCL_64, nullptr, yb, nullptr);
  // LN2 fused: out = LN(x1 + scalar*(yb0+yb1+b2))
  ln2_fused_kernel<<<8192, 256, 0, stream>>>(
      yb, yb + (size_t)8192 * 1024, x1b, b2, scalar, ln2w, ln2b, out);
}